// Round 9
// baseline (272.776 us; speedup 1.0000x reference)
//
#include <hip/hip_runtime.h>
#include <stdint.h>

// LocallyConnected2D: out[b,f,or,oc] = relu( sum_{c,kh,kw} x[b,c,2or+kh,2oc+kw]*W[f,c,2or+kh,2oc+kw] + bias )
// bias raw-reshape: bias_flat[f*OR*OC + or*OC + oc]
//
// B=32 C=32 H=128 W=128 F=64 OR=OC=64.
//
// R13: X in LDS (multicast), W global->VGPR same-iteration. 
// Post-mortem ledger:
//  - R9 counter normalization ERROR found: SQ_LDS_BANK_CONFLICT=4.19M is GPU-TOTAL =
//    16k cy/CU = 1.8% of runtime. Conflicts never mattered. Per-CU budget of R9's 235k cy:
//    LDS reads 98k (42%), VALU 52k (22%, matches VALUBusy), staging ~50k, barriers ~20k.
//  - R12 (4 domains, 1 barrier/chunk) = 109us -> convoy theory dead.
//  - R11 (no LDS at all) = 170us -> X MUST be LDS-multicast (16x traffic amplification).
//  - R8 (W in pinned cross-iter registers) = spill disaster. W-from-global is right
//    (zero cross-wave reuse: 8 consumers of each W element are lanes of ONE wave; the
//    coalescer merges the 8-lane-dup load to one 128-B line fetch, each line read once
//    kernel-wide) -- but consume SAME-ITERATION, no register carrying across iters.
// This halves ds_read_b128 count (the 42% term) and halves staged bytes.
// vmcnt (in-order): per-iter issue = [wb(it) x8] wait barrier [X(it+2) x1].
// Newer-than-X(it) at wait = X(it+1)+wb(it) = 9 -> vmcnt(9); it=31 -> vmcnt(8).
// Compiler's own wb-use waits retire older X's each iter; no full drains vs unmet loads.
// Verify: LDS 24576; VGPR ~96-120 (64+WRITE-balloon = spill -> revert); dur ~65-80us;
// absmax bit-identical.

#define CC  32
#define HH  128
#define WWD 128
#define FF  64
#define ORR 64
#define OCC 64
#define NIT 32                 // chunks = channels
#define HW  (HH * WWD)         // 16384 floats per channel
#define CHW (CC * HH * WWD)    // 524288 floats per f plane

#define SB() __builtin_amdgcn_sched_barrier(0)

__global__ __launch_bounds__(512, 4) void lc2d_kernel(
    const float* __restrict__ x, const float* __restrict__ wgt,
    const float* __restrict__ bias, float* __restrict__ out)
{
    __shared__ __align__(16) float Xs[3][2048];   // 24 KB: 3-deep ring of 8 KB X chunks

    const int tid  = threadIdx.x;
    const int id   = blockIdx.x;           // [0,512)
    const int fblk = id >> 8;              // which 32-f half
    const int low  = id & 255;
    // ids differing by 128 share 128-B output lines and the same XCD (128%8==0);
    // pair (id, id+256) shares the x tile on the same XCD (256%8==0).
    const int oct = ((low & 1) << 1) | (low >> 7);   // 0..3 -> oc0 = oct*16
    const int orr = (low >> 1) & 63;
    const int w0  = oct * 32;                         // 32 w-floats, 128-B aligned
    const int h0  = orr * 2;

    const int lane = tid & 63;
    const int wv   = tid >> 6;        // wave 0..7
    const int chk  = lane & 7;        // 16-B chunk within a 128-B row
    const int sub  = lane >> 3;       // row within this wave's 8-row slot

    // ---- X staging (R9 verified swizzle): wave wv covers slice s=wv>>2, quarter wv&3;
    // source b = sub*4 + (wv&3). Granule (b,chk) of slice s lands at per-slice position
    // (b&3)*64 + (b>>2)*8 + chk -> compute reads are lane-linear, conflict-free.
    const int skh = wv >> 2;
    const int bsw = sub * 4 + (wv & 3);
    const float* gx = x + (((bsw * CC) * HH) + h0 + skh) * WWD + w0 + chk * 4;

    auto issueX = [&](int p) {
        __builtin_amdgcn_global_load_lds(
            (const __attribute__((address_space(1))) void*)gx,
            (__attribute__((address_space(3))) void*)(&Xs[p][wv * 256]), 16, 0, 0);
        gx += HW;                      // next channel
    };

    // ---- compute mapping: ocg = w 4-float chunk (2 oc), bg -> 4 b, wv -> 4 f
    const int ocg = tid & 7;
    const int bg  = (tid >> 3) & 7;

    // W source for f = fblk*32 + wv*4 + q: 8 ocg-lanes x 16 B = one 128-B line,
    // duplicated across 8 bg-lanes (coalescer merges). Advanced by HW per chunk.
    const float* wp = wgt + (size_t)(fblk * 32 + wv * 4) * CHW + (size_t)h0 * WWD + w0 + ocg * 4;

    float acc0[4][4], acc1[4][4];          // [i=b][q=f], oc even / oc odd
#pragma unroll
    for (int i = 0; i < 4; ++i)
#pragma unroll
        for (int q = 0; q < 4; ++q) { acc0[i][q] = 0.f; acc1[i][q] = 0.f; }

    // prologue: X0, X1 in flight
    issueX(0); issueX(1);

    for (int it = 0; it < NIT; ++it) {
        // ---- wb(it): 8 global loads (2 s x 4 q), issued BEFORE the counted wait
        float4 wb0[4], wb1[4];
#pragma unroll
        for (int q = 0; q < 4; ++q) wb0[q] = *(const float4*)(wp + (size_t)q * CHW);
#pragma unroll
        for (int q = 0; q < 4; ++q) wb1[q] = *(const float4*)(wp + (size_t)q * CHW + WWD);
        SB();                              // pin wb issue before the counted vmcnt
        // X(it) ready: newer ops = X(it+1) + wb(it) = 9 (it=31: wb only = 8)
        if (it < NIT - 1) asm volatile("s_waitcnt vmcnt(9)");
        else              asm volatile("s_waitcnt vmcnt(8)");
        SB();
        __builtin_amdgcn_s_barrier();      // everyone's X(it) staged; buf (it-1)%3 free
        SB();
        if (it + 2 < NIT) issueX((it + 2) % 3);
        SB();

        const float* Xp = Xs[it % 3];
        {   // s = 0
            const float4* xr = (const float4*)(Xp + (lane << 2));
            float4 xa[4];
#pragma unroll
            for (int i = 0; i < 4; ++i) xa[i] = xr[i * 64];  // b = bg*4 + i
#pragma unroll
            for (int i = 0; i < 4; ++i)
#pragma unroll
                for (int q = 0; q < 4; ++q) {
                    acc0[i][q] = fmaf(xa[i].x, wb0[q].x, acc0[i][q]);
                    acc0[i][q] = fmaf(xa[i].y, wb0[q].y, acc0[i][q]);
                    acc1[i][q] = fmaf(xa[i].z, wb0[q].z, acc1[i][q]);
                    acc1[i][q] = fmaf(xa[i].w, wb0[q].w, acc1[i][q]);
                }
        }
        {   // s = 1
            const float4* xr = (const float4*)(Xp + 1024 + (lane << 2));
            float4 xa[4];
#pragma unroll
            for (int i = 0; i < 4; ++i) xa[i] = xr[i * 64];
#pragma unroll
            for (int i = 0; i < 4; ++i)
#pragma unroll
                for (int q = 0; q < 4; ++q) {
                    acc0[i][q] = fmaf(xa[i].x, wb1[q].x, acc0[i][q]);
                    acc0[i][q] = fmaf(xa[i].y, wb1[q].y, acc0[i][q]);
                    acc1[i][q] = fmaf(xa[i].z, wb1[q].z, acc1[i][q]);
                    acc1[i][q] = fmaf(xa[i].w, wb1[q].w, acc1[i][q]);
                }
        }
        wp += HW;                          // next channel
    }

    // ---- epilogue: bias (raw reshape [F][OR][OC]) + relu, float2 per (b,f)
    const int oc0 = oct * 16 + ocg * 2;
#pragma unroll
    for (int q = 0; q < 4; ++q) {
        const int f = fblk * 32 + wv * 4 + q;
        const float2 bv = *(const float2*)(bias + f * (ORR * OCC) + orr * OCC + oc0);
#pragma unroll
        for (int i = 0; i < 4; ++i) {
            const int b = bg * 4 + i;
            float2 o;
            o.x = fmaxf(acc0[i][q] + bv.x, 0.f);
            o.y = fmaxf(acc1[i][q] + bv.y, 0.f);
            *(float2*)(out + (((b * FF + f) * ORR + orr) * OCC) + oc0) = o;
        }
    }
}

extern "C" void kernel_launch(void* const* d_in, const int* in_sizes, int n_in,
                              void* d_out, int out_size, void* d_ws, size_t ws_size,
                              hipStream_t stream) {
    (void)in_sizes; (void)n_in; (void)d_ws; (void)ws_size; (void)out_size;
    const float* x    = (const float*)d_in[0];
    const float* wgt  = (const float*)d_in[1];
    const float* bias = (const float*)d_in[2];
    float* out        = (float*)d_out;
    lc2d_kernel<<<dim3(512, 1, 1), dim3(512, 1, 1), 0, stream>>>(x, wgt, bias, out);
}